// Round 3
// baseline (1625.057 us; speedup 1.0000x reference)
//
#include <hip/hip_runtime.h>

#define T_DIM 512
#define N_REC 256
#define N_IN  10
#define N_OUT 3
#define BCH   4      // batch rows per block
#define NBLK  256    // 1024 / BCH
#define NTHR  512    // 8 waves

typedef __attribute__((ext_vector_type(8))) short short8;
typedef __attribute__((ext_vector_type(4))) float float4v;

__device__ __forceinline__ unsigned short f2bf(float f) {
    unsigned int u = __builtin_bit_cast(unsigned int, f);
    unsigned int r = (u + 0x7FFFu + ((u >> 16) & 1u)) >> 16;
    return (unsigned short)r;
}

__global__ __launch_bounds__(NTHR) void rnn_kernel(
    const float* __restrict__ x, const float* __restrict__ noise,
    const float* __restrict__ W_in, const float* __restrict__ W_rec,
    const float* __restrict__ W_out_w, const float* __restrict__ W_out_b,
    const float* __restrict__ bias, float* __restrict__ out,
    float* __restrict__ out_l2)
{
    const int tid  = threadIdx.x;
    const int wave = tid >> 6;
    const int lane = tid & 63;
    const int b0   = blockIdx.x * BCH;
    const int n0   = wave * 32;          // this wave's output-column base

    // LDS: double-buffered r (bf16, padded stride 264), u, x, z partials
    __shared__ unsigned short rbuf[2][BCH][264];
    __shared__ float ubuf[2][BCH][N_REC];
    __shared__ float xlds[2][BCH][N_IN];
    __shared__ float zbuf[2][8][12];
    __shared__ float wred[8];

    // zero r buffers (r0 = 0)
    {
        unsigned short* rz = &rbuf[0][0][0];
        for (int i = tid; i < 2 * BCH * 264; i += NTHR) rz[i] = 0;
    }

    // ---- persistent W_rec B-fragments in VGPRs (this wave's 32 cols) ----
    // B[k][col] = W_rec[col][k]; lane: col = n0 + f*16 + (lane&15), k = kc*32 + (lane>>4)*8 + j
    short8 wfr[16];  // [kc*2 + f]
    {
        const int cl = lane & 15;
        const int ks = (lane >> 4) * 8;
        #pragma unroll
        for (int f = 0; f < 2; ++f) {
            const float* wrow = W_rec + (size_t)(n0 + f * 16 + cl) * N_REC + ks;
            #pragma unroll
            for (int kc = 0; kc < 8; ++kc) {
                short8 v;
                #pragma unroll
                for (int j = 0; j < 8; ++j) v[j] = (short)f2bf(wrow[kc * 32 + j]);
                wfr[kc * 2 + f] = v;
            }
        }
    }

    // ---- persistent per-thread u-compute constants (2 neurons/thread) ----
    const int un = (2 * tid) & 255;   // neuron pair base (even)
    const int ub = tid >> 7;          // batch row (0..3)
    float win0[N_IN], win1[N_IN];
    #pragma unroll
    for (int i = 0; i < N_IN; ++i) {
        win0[i] = W_in[un * N_IN + i];
        win1[i] = W_in[(un + 1) * N_IN + i];
    }
    const float bias0 = bias[un], bias1 = bias[un + 1];

    // ---- epilogue-lane persistent state (lanes 0..15 hold C rows 0..3) ----
    float wout[2][N_OUT];
    if (lane < 16) {
        #pragma unroll
        for (int f = 0; f < 2; ++f)
            #pragma unroll
            for (int j = 0; j < N_OUT; ++j)
                wout[f][j] = W_out_w[j * N_REC + n0 + f * 16 + lane];
    }
    float rp[2][BCH];
    #pragma unroll
    for (int f = 0; f < 2; ++f)
        #pragma unroll
        for (int b = 0; b < BCH; ++b) rp[f][b] = 0.f;
    float l2acc = 0.f;

    const float wob = (tid < 12) ? W_out_b[tid % 3] : 0.f;

    // ---- prologue: prefetch t=0 noise + x ----
    const float2* noise_base =
        (const float2*)(noise + (size_t)(b0 + ub) * T_DIM * N_REC + un);
    float2 nr = noise_base[0];
    float xnext = 0.f;
    if (tid < BCH * N_IN) {
        xlds[0][tid / N_IN][tid % N_IN] =
            x[(size_t)(b0 + tid / N_IN) * T_DIM * N_IN + tid % N_IN];
    }
    __syncthreads();

    for (int t = 0; t < T_DIM; ++t) {
        const int p = t & 1;
        const int tn = (t + 1 < T_DIM) ? t + 1 : T_DIM - 1;

        // ---------- Phase A ----------
        if (tid < BCH * N_IN)   // issue x prefetch for t+1
            xnext = x[(size_t)(b0 + tid / N_IN) * T_DIM * N_IN + (size_t)tn * N_IN + tid % N_IN];

        {   // u(t) = noise + bias + x @ W_in^T   (all 512 threads, 2 neurons each)
            float ux = nr.x + bias0, uy = nr.y + bias1;
            #pragma unroll
            for (int i = 0; i < N_IN; ++i) {
                float xv = xlds[p][ub][i];
                ux += xv * win0[i];
                uy += xv * win1[i];
            }
            ubuf[p][ub][un]     = ux;
            ubuf[p][ub][un + 1] = uy;
        }
        // issue noise prefetch for t+1 (dwordx2)
        nr = noise_base[(size_t)tn * (N_REC / 2)];

        if (t > 0 && tid < 12) {   // finalize z(t-1)
            float z = wob;
            #pragma unroll
            for (int w = 0; w < 8; ++w) z += zbuf[p ^ 1][w][tid];
            out[((size_t)(b0 + tid / 3) * T_DIM + (t - 1)) * N_OUT + tid % 3] = z;
        }
        __syncthreads();

        // ---------- Phase C: MFMA  acc = r @ W_rec^T (this wave's 32 cols) ----------
        float4v acc0 = {0.f, 0.f, 0.f, 0.f}, acc1 = {0.f, 0.f, 0.f, 0.f};
        {
            int rowc = lane & 15; if (rowc >= BCH) rowc = 0;   // clamp -> duplicate row 0
            const unsigned short* rrow = &rbuf[p][rowc][(lane >> 4) * 8];
            #pragma unroll
            for (int kc = 0; kc < 8; ++kc) {
                short8 af = *(const short8*)(rrow + kc * 32);
                acc0 = __builtin_amdgcn_mfma_f32_16x16x32_bf16(af, wfr[kc * 2 + 0], acc0, 0, 0, 0);
                acc1 = __builtin_amdgcn_mfma_f32_16x16x32_bf16(af, wfr[kc * 2 + 1], acc1, 0, 0, 0);
            }
        }

        // ---------- Phase D: state update + outputs (lanes 0..15, rows=regs) ----------
        if (lane < 16) {
            float zp[12];
            #pragma unroll
            for (int i = 0; i < 12; ++i) zp[i] = 0.f;
            #pragma unroll
            for (int f = 0; f < 2; ++f) {
                const int col = n0 + f * 16 + lane;
                #pragma unroll
                for (int b = 0; b < BCH; ++b) {
                    float v = (f ? acc1[b] : acc0[b]) + ubuf[p][b][col];
                    v = v > 0.f ? v : 0.f;
                    float rn = 0.8f * rp[f][b] + 0.2f * v;
                    rp[f][b] = rn;
                    rbuf[p ^ 1][b][col] = f2bf(rn);
                    l2acc += rn * rn;
                    #pragma unroll
                    for (int j = 0; j < N_OUT; ++j) zp[b * 3 + j] += wout[f][j] * rn;
                }
            }
            #pragma unroll
            for (int m = 1; m < 16; m <<= 1) {
                #pragma unroll
                for (int i = 0; i < 12; ++i) zp[i] += __shfl_xor(zp[i], m, 64);
            }
            if (lane == 0) {
                #pragma unroll
                for (int i = 0; i < 12; ++i) zbuf[p][wave][i] = zp[i];
            }
        }
        if (tid < BCH * N_IN) xlds[p ^ 1][tid / N_IN][tid % N_IN] = xnext;
        __syncthreads();
    }

    // final z(T-1)
    if (tid < 12) {
        float z = wob;
        #pragma unroll
        for (int w = 0; w < 8; ++w) z += zbuf[(T_DIM - 1) & 1][w][tid];
        out[((size_t)(b0 + tid / 3) * T_DIM + (T_DIM - 1)) * N_OUT + tid % 3] = z;
    }

    // l2 reduction: lanes 16+ contribute 0
    #pragma unroll
    for (int m = 1; m < 64; m <<= 1) l2acc += __shfl_xor(l2acc, m, 64);
    if (lane == 0) wred[wave] = l2acc;
    __syncthreads();
    if (tid == 0) {
        float s = 0.f;
        #pragma unroll
        for (int w = 0; w < 8; ++w) s += wred[w];
        atomicAdd(out_l2, s * (1.0f / ((float)T_DIM * 1024.f * 256.f)));
    }
}

extern "C" void kernel_launch(void* const* d_in, const int* in_sizes, int n_in,
                              void* d_out, int out_size, void* d_ws, size_t ws_size,
                              hipStream_t stream) {
    const float* x       = (const float*)d_in[0];
    const float* noise   = (const float*)d_in[1];
    const float* W_in    = (const float*)d_in[2];
    const float* W_rec   = (const float*)d_in[3];
    const float* W_out_w = (const float*)d_in[4];
    const float* W_out_b = (const float*)d_in[5];
    const float* bias    = (const float*)d_in[6];
    float* out    = (float*)d_out;
    float* out_l2 = out + (size_t)1024 * T_DIM * N_OUT;

    hipMemsetAsync(out_l2, 0, sizeof(float), stream);
    rnn_kernel<<<NBLK, NTHR, 0, stream>>>(x, noise, W_in, W_rec, W_out_w,
                                          W_out_b, bias, out, out_l2);
}